// Round 10
// baseline (112.173 us; speedup 1.0000x reference)
//
#include <hip/hip_runtime.h>

// TripletAttention on MI355X — 4-kernel pipeline. PROBE: REP_F=8 on kF only
// (kF's per-rep HBM writes don't L3-warm -> unbiased per-iter cost + counters).
// Ship: kF LN-finalize parallelized (was 128 serial loads on one lane).
// y = x * T[b,h,w] with T = 1 + S*cross*g; attention is rank-4.

#define B_   32
#define H_   32
#define W_   32
#define C_   256
#define N_   1024           // H_*W_
#define HWC_ (32*32*256)

#define REP_F 8

// ws layout (float offsets)
#define OFF_XW    0          // [B][H][C]  mean over w
#define OFF_XH    262144     // [B][W][C]  mean over h
#define OFF_MC    524288     // [B][N]     mean over c
#define OFF_M2    557056     // [B][N]     sum of x^2 over c
#define OFF_T     589824     // [B][N]
#define OFF_HA    622592     // [B][32]
#define OFF_WA    623616     // [B][32]
#define OFF_CA    624640     // [B]
#define OFF_G     624672     // [B]
#define OFF_CST   624704     // 24 consts
#define OFF_LNP   624736     // [B][64][2] LN partials
#define WS_FLOATS 628832

#define NCOPY   4
#define CSTRIDE 1028         // 4-float aligned; banks advance by 4 per copy

#if __has_builtin(__builtin_amdgcn_exp2f)
#define EXP2F(x) __builtin_amdgcn_exp2f(x)
#else
#define EXP2F(x) exp2f(x)
#endif

__device__ __forceinline__ float sigm_(float v){ return 1.f/(1.f + __expf(-v)); }
__device__ __forceinline__ float dot4_(float4 a, float4 b){
  return a.x*b.x + a.y*b.y + a.z*b.z + a.w*b.w;
}

// ---------------- Kernel AB: blocks [0,1024): per-(b,h) slab -> xw, mc, m2
//                             blocks [1024,2048): per-(b,w) column -> xh
__global__ __launch_bounds__(256) void kAB(const float* __restrict__ x, float* __restrict__ ws){
  __shared__ float4 sl4[256];
  const int blk = blockIdx.x;
  const int tid = threadIdx.x, lane = tid & 63, wv = tid >> 6;
  if (blk < 1024){
    const int b = blk >> 5, h = blk & 31;
    const float* xp = x + (size_t)(b*H_ + h)*(W_*C_);
    float4 v[8];
    #pragma unroll
    for (int k = 0; k < 8; ++k) v[k] = ((const float4*)xp)[tid + k*256];
    #pragma unroll
    for (int k = 0; k < 8; ++k){
      float s = v[k].x + v[k].y + v[k].z + v[k].w;
      float q = v[k].x*v[k].x + v[k].y*v[k].y + v[k].z*v[k].z + v[k].w*v[k].w;
      #pragma unroll
      for (int d = 1; d < 64; d <<= 1){ s += __shfl_xor(s, d); q += __shfl_xor(q, d); }
      if (lane == 0){
        const int w = k*4 + wv;
        ws[OFF_MC + b*N_ + h*W_ + w] = s * (1.f/C_);
        ws[OFF_M2 + b*N_ + h*W_ + w] = q;
      }
    }
    float4 a = v[0];
    #pragma unroll
    for (int k = 1; k < 8; ++k){ a.x += v[k].x; a.y += v[k].y; a.z += v[k].z; a.w += v[k].w; }
    sl4[tid] = a;
    __syncthreads();
    if (tid < 64){
      const float4 p0 = sl4[tid], p1 = sl4[tid+64], p2 = sl4[tid+128], p3 = sl4[tid+192];
      float4 o;
      o.x = (p0.x+p1.x+p2.x+p3.x)*(1.f/W_);
      o.y = (p0.y+p1.y+p2.y+p3.y)*(1.f/W_);
      o.z = (p0.z+p1.z+p2.z+p3.z)*(1.f/W_);
      o.w = (p0.w+p1.w+p2.w+p3.w)*(1.f/W_);
      ((float4*)(ws + OFF_XW + (b*H_ + h)*C_))[tid] = o;
    }
  } else {
    const int blk2 = blk - 1024, b = blk2 >> 5, w = blk2 & 31;
    const int hh = tid >> 6, c4 = (tid & 63)*4;
    const float* xp = x + (size_t)b*HWC_ + (size_t)w*C_ + c4;
    float4 acc = {0.f,0.f,0.f,0.f};
    #pragma unroll
    for (int hb = 0; hb < 8; ++hb){
      const int h = hb*4 + hh;
      const float4 v = *(const float4*)(xp + (size_t)h*(W_*C_));
      acc.x += v.x; acc.y += v.y; acc.z += v.z; acc.w += v.w;
    }
    sl4[tid] = acc;
    __syncthreads();
    if (tid < 64){
      const float4 a = sl4[tid], b2 = sl4[tid+64], c = sl4[tid+128], d = sl4[tid+192];
      float4 o;
      o.x = (a.x+b2.x+c.x+d.x)*(1.f/H_);
      o.y = (a.y+b2.y+c.y+d.y)*(1.f/H_);
      o.z = (a.z+b2.z+c.z+d.z)*(1.f/H_);
      o.w = (a.w+b2.w+c.w+d.w)*(1.f/H_);
      *(float4*)&ws[OFF_XH + (b*W_ + w)*C_ + tid*4] = o;
    }
  }
}

// ---------------- Kernel C: one wave per (profile,row) gate output
// grid (B_, 17): y in [0,8) -> ha rows, y in [8,16) -> wa rows, y==16 -> ca/g/consts
__global__ __launch_bounds__(256) void kC(float* __restrict__ ws,
  const float* __restrict__ cc1_w, const float* __restrict__ cc1_b, const float* __restrict__ cc3_dw,
  const float* __restrict__ cc3_pw, const float* __restrict__ cc3_b, const float* __restrict__ ccd_w, const float* __restrict__ ccd_b,
  const float* __restrict__ ch1_w, const float* __restrict__ ch1_b, const float* __restrict__ ch3_dw,
  const float* __restrict__ ch3_pw, const float* __restrict__ ch3_b, const float* __restrict__ chd_w, const float* __restrict__ chd_b,
  const float* __restrict__ cw1_w, const float* __restrict__ cw1_b, const float* __restrict__ cw3_dw,
  const float* __restrict__ cw3_pw, const float* __restrict__ cw3_b, const float* __restrict__ cwd_w, const float* __restrict__ cwd_b,
  const float* __restrict__ branch_w, const float* __restrict__ d1_w, const float* __restrict__ d1_b,
  const float* __restrict__ d2_w, const float* __restrict__ d2_b,
  const float* __restrict__ q_w, const float* __restrict__ q_b, const float* __restrict__ k_w, const float* __restrict__ k_b,
  const float* __restrict__ v_w, const float* __restrict__ v_b, const float* __restrict__ o_w, const float* __restrict__ o_b)
{
  const int b = blockIdx.x, y = blockIdx.y;
  const int tid = threadIdx.x, lane = tid & 63, wv = tid >> 6;

  if (y < 16){
    const int prof = y >> 3;                 // 0: height gates from xw, 1: width gates from xh
    const int h = ((y & 7) << 2) | wv;       // 0..31, one per wave
    const float* P  = ws + (prof ? OFF_XH : OFF_XW) + b*(32*C_);
    const float* w1 = prof ? cw1_w  : ch1_w;
    const float* b1 = prof ? cw1_b  : ch1_b;
    const float* dw = prof ? cw3_dw : ch3_dw;
    const float* pw = prof ? cw3_pw : ch3_pw;
    const float* b3 = prof ? cw3_b  : ch3_b;
    const float* wd = prof ? cwd_w  : chd_w;
    const float* bd = prof ? cwd_b  : chd_b;
    const int c4 = lane*4;
    const float4 z4 = {0.f,0.f,0.f,0.f};
    const float4 r0  = *(const float4*)(P + h*C_ + c4);
    const float4 rm1 = (h > 0)  ? *(const float4*)(P + (h-1)*C_ + c4) : z4;
    const float4 rp1 = (h < 31) ? *(const float4*)(P + (h+1)*C_ + c4) : z4;
    const float4 rm2 = (h > 1)  ? *(const float4*)(P + (h-2)*C_ + c4) : z4;
    const float4 rp2 = (h < 30) ? *(const float4*)(P + (h+2)*C_ + c4) : z4;
    const float4 w1q = *(const float4*)(w1 + c4);
    const float4 d3  = *(const float4*)(dw + 3*C_ + c4);
    const float4 d4  = *(const float4*)(dw + 4*C_ + c4);
    const float4 d5  = *(const float4*)(dw + 5*C_ + c4);
    const float4 pwq = *(const float4*)(pw + c4);
    const float4 g3  = *(const float4*)(wd + 3*C_ + c4);
    const float4 g4  = *(const float4*)(wd + 4*C_ + c4);
    const float4 g5  = *(const float4*)(wd + 5*C_ + c4);
    float s1 = dot4_(r0, w1q);
    float4 dv;
    dv.x = rm1.x*d3.x + r0.x*d4.x + rp1.x*d5.x;
    dv.y = rm1.y*d3.y + r0.y*d4.y + rp1.y*d5.y;
    dv.z = rm1.z*d3.z + r0.z*d4.z + rp1.z*d5.z;
    dv.w = rm1.w*d3.w + r0.w*d4.w + rp1.w*d5.w;
    float s3 = dot4_(dv, pwq);
    float sd = (rm2.x*g3.x + r0.x*g4.x + rp2.x*g5.x)
             + (rm2.y*g3.y + r0.y*g4.y + rp2.y*g5.y)
             + (rm2.z*g3.z + r0.z*g4.z + rp2.z*g5.z)
             + (rm2.w*g3.w + r0.w*g4.w + rp2.w*g5.w);
    #pragma unroll
    for (int d = 1; d < 64; d <<= 1){ s1 += __shfl_xor(s1,d); s3 += __shfl_xor(s3,d); sd += __shfl_xor(sd,d); }
    if (lane == 0)
      ws[(prof ? OFF_WA : OFF_HA) + b*32 + h] =
          (sigm_(s1 + b1[0]) + sigm_(s3 + b3[0]) + sigm_(sd + bd[0])) * (1.f/3.f);
    return;
  }

  // y == 16: gvec -> ca (wave0), g (wave1, parallel SE); consts (wave2, b==0)
  __shared__ float gvec[C_];
  { float s = 0.f;
    const float* P = ws + OFF_XW + b*(32*C_);
    #pragma unroll
    for (int h = 0; h < H_; ++h) s += P[h*C_ + tid];
    gvec[tid] = s * (1.f/H_); }
  __syncthreads();

  if (wv == 0){
    float s1 = 0.f, s3 = 0.f, sd = 0.f;
    #pragma unroll
    for (int k = 0; k < 4; ++k){
      const int c = lane + k*64;
      const float v = gvec[c];
      s1 = fmaf(v, cc1_w[c], s1);
      s3 = fmaf(v*cc3_dw[4*C_+c], cc3_pw[c], s3);
      sd = fmaf(v, ccd_w[4*C_+c], sd);
    }
    #pragma unroll
    for (int d = 1; d < 64; d <<= 1){ s1 += __shfl_xor(s1,d); s3 += __shfl_xor(s3,d); sd += __shfl_xor(sd,d); }
    if (lane == 0)
      ws[OFF_CA + b] = (sigm_(s1+cc1_b[0]) + sigm_(s3+cc3_b[0]) + sigm_(sd+ccd_b[0])) * (1.f/3.f);
  } else if (wv == 1){
    // parallel SE: lane = (cg, r): 4 channel-groups x 16 hidden units
    const int r16 = lane & 15, cg = lane >> 4;
    float s = 0.f;
    #pragma unroll
    for (int i = 0; i < 64; ++i){
      const int c = cg*64 + i;
      s = fmaf(gvec[c], d1_w[c*16 + r16], s);
    }
    s += __shfl_xor(s, 16); s += __shfl_xor(s, 32);
    float t = fmaxf(s + d1_b[r16], 0.f) * d2_w[r16];
    t += __shfl_xor(t, 1); t += __shfl_xor(t, 2); t += __shfl_xor(t, 4); t += __shfl_xor(t, 8);
    if (lane == 0) ws[OFF_G + b] = sigm_(t + d2_b[0]);
  } else if (wv == 2 && b == 0){
    if (lane < 16){
      const int i = lane >> 2, j = lane & 3;
      float s = 0.f;
      #pragma unroll
      for (int d = 0; d < 8; ++d){
        const float qv = (i < 3) ? q_w[i*8+d] : q_b[d];
        const float kv = (j < 3) ? k_w[j*8+d] : k_b[d];
        s = fmaf(qv, kv, s);
      }
      ws[OFF_CST + i*4 + j] = s * 0.51010305898f;   // log2(e)/sqrt(8)
    } else if (lane < 19){
      const int i = lane - 16;
      float s = 0.f;
      #pragma unroll
      for (int d = 0; d < 8; ++d) s = fmaf(v_w[i*8+d], o_w[d], s);
      ws[OFF_CST + lane] = s;
    } else if (lane == 19){
      float s = o_b[0];
      #pragma unroll
      for (int d = 0; d < 8; ++d) s = fmaf(v_b[d], o_w[d], s);
      ws[OFF_CST + 19] = s;
    } else if (lane == 20){
      const float b0 = branch_w[0], b1 = branch_w[1], b2 = branch_w[2];
      const float mx = fmaxf(b0, fmaxf(b1, b2));
      const float e0 = __expf(b0-mx), e1 = __expf(b1-mx), e2 = __expf(b2-mx);
      const float inv = 1.f/(e0+e1+e2);
      ws[OFF_CST+20] = e0*inv; ws[OFF_CST+21] = e1*inv; ws[OFF_CST+22] = e2*inv;
      ws[OFF_CST+23] = 0.f;
    }
  }
}

// ---------------- Kernel D v3: rank-4 attention with folded projection
__global__ __launch_bounds__(256, 4) void kD(float* __restrict__ ws){
  __shared__ __align__(16) float mcs[NCOPY*CSTRIDE];
  __shared__ __align__(16) float qs [NCOPY*CSTRIDE];
  __shared__ float ha_s[32], wa_s[32], cst[24], sc[2], red[8];
  const int blk = blockIdx.x, b = blk >> 6, rblk = blk & 63;
  const int tid = threadIdx.x, lane = tid & 63, wv = tid >> 6;
  const int r = tid >> 4, sub = tid & 15;     // 16 rows/block, 16 subs/row
  const int n = rblk*16 + r;
  const int hn = n >> 5, wn = n & 31;

  const float4 v  = ((const float4*)(ws + OFF_MC + b*N_))[tid];
  const float m2v = ws[OFF_M2 + b*N_ + n];
  const float mcn = ws[OFF_MC + b*N_ + n];
  if (tid < 32){ ha_s[tid] = ws[OFF_HA + b*32 + tid]; wa_s[tid] = ws[OFF_WA + b*32 + tid]; }
  else if (tid >= 64 && tid < 88) cst[tid-64] = ws[OFF_CST + (tid-64)];
  else if (tid == 96){ sc[0] = ws[OFF_CA + b]; sc[1] = ws[OFF_G + b]; }
  #pragma unroll
  for (int cp = 0; cp < NCOPY; ++cp) *(float4*)&mcs[cp*CSTRIDE + tid*4] = v;
  __syncthreads();

  const float ca = sc[0], gg = sc[1];
  {
    const int hm0 = tid >> 3;
    const int wm0 = (tid*4) & 31;
    const float base = ca*cst[16] + cst[17]*ha_s[hm0];
    float4 q;
    q.x = v.x * (base + cst[18]*wa_s[wm0+0]);
    q.y = v.y * (base + cst[18]*wa_s[wm0+1]);
    q.z = v.z * (base + cst[18]*wa_s[wm0+2]);
    q.w = v.w * (base + cst[18]*wa_s[wm0+3]);
    #pragma unroll
    for (int cp = 0; cp < NCOPY; ++cp) *(float4*)&qs[cp*CSTRIDE + tid*4] = q;
  }
  __syncthreads();

  const float u0 = mcn*ca, u1 = mcn*ha_s[hn], u2 = mcn*wa_s[wn];
  const float p0 = u0*cst[0] + u1*cst[4] + u2*cst[8]  + cst[12];
  const float p1 = u0*cst[1] + u1*cst[5] + u2*cst[9]  + cst[13];
  const float p2 = u0*cst[2] + u1*cst[6] + u2*cst[10] + cst[14];
  const float p3 = u0*cst[3] + u1*cst[7] + u2*cst[11] + cst[15];
  const float pc = p0 * ca;

  float Z = 0.f, ACC = 0.f;
  const float* mbase = &mcs[(sub & 3)*CSTRIDE];
  const float* qbase = &qs [(sub & 3)*CSTRIDE];
  #pragma unroll
  for (int j = 0; j < 2; ++j){
    const int hm = sub*2 + j;
    const float th = fmaf(p1, ha_s[hm], pc);
    const float* mrow = mbase + hm*32;
    const float* qrow = qbase + hm*32;
    #pragma unroll
    for (int wm = 0; wm < 32; wm += 4){
      const float4 m4 = *(const float4*)&mrow[wm];
      const float4 q4 = *(const float4*)&qrow[wm];
      const float4 w4 = *(const float4*)&wa_s[wm];
      { const float vv = fmaf(p2, w4.x, th); const float ee = EXP2F(fmaf(m4.x, vv, p3)); Z += ee; ACC = fmaf(ee, q4.x, ACC); }
      { const float vv = fmaf(p2, w4.y, th); const float ee = EXP2F(fmaf(m4.y, vv, p3)); Z += ee; ACC = fmaf(ee, q4.y, ACC); }
      { const float vv = fmaf(p2, w4.z, th); const float ee = EXP2F(fmaf(m4.z, vv, p3)); Z += ee; ACC = fmaf(ee, q4.z, ACC); }
      { const float vv = fmaf(p2, w4.w, th); const float ee = EXP2F(fmaf(m4.w, vv, p3)); Z += ee; ACC = fmaf(ee, q4.w, ACC); }
    }
  }
  #pragma unroll
  for (int d = 1; d < 16; d <<= 1){
    Z   += __shfl_xor(Z, d);
    ACC += __shfl_xor(ACC, d);
  }

  float t1 = 0.f, t2 = 0.f;
  if (sub == 0){
    const float dot = ACC / Z + cst[19];
    const float cross = 1.f / (1.f + __expf(-dot));
    const float S = cst[20]*ca + cst[21]*ha_s[hn] + cst[22]*wa_s[wn];
    const float T = fmaf(S*cross, gg, 1.f);
    ws[OFF_T + b*N_ + n] = T;
    t1 = T * mcn * (float)C_;
    t2 = T * T * m2v;
  }
  #pragma unroll
  for (int d = 1; d < 64; d <<= 1){ t1 += __shfl_xor(t1,d); t2 += __shfl_xor(t2,d); }
  if (lane == 0){ red[wv] = t1; red[4+wv] = t2; }
  __syncthreads();
  if (tid == 0){
    ws[OFF_LNP + (b*64 + rblk)*2 + 0] = red[0]+red[1]+red[2]+red[3];
    ws[OFF_LNP + (b*64 + rblk)*2 + 1] = red[4]+red[5]+red[6]+red[7];
  }
}

// ---------------- Kernel F v2: parallel LN finalize + stream  [REP_F probe]
__global__ __launch_bounds__(256) void kF(const float* __restrict__ x, const float* __restrict__ gamma,
                                          const float* __restrict__ beta, const float* __restrict__ ws,
                                          float* __restrict__ out){
  const int blk = blockIdx.x, b = blk >> 5, h = blk & 31;
  const int tid = threadIdx.x;
  __shared__ float a1s[32];
  __shared__ float mu_r[2];
  for (int rep = 0; rep < REP_F; ++rep){
    asm volatile("" ::: "memory");
    if (tid < 64){
      // lane i holds LNP pair i; two 6-step butterfly reduces
      float s1 = ws[OFF_LNP + (b*64 + tid)*2 + 0];
      float s2 = ws[OFF_LNP + (b*64 + tid)*2 + 1];
      #pragma unroll
      for (int d = 1; d < 64; d <<= 1){ s1 += __shfl_xor(s1, d); s2 += __shfl_xor(s2, d); }
      if (tid == 0){
        const float mu  = s1 * (1.f/HWC_);
        const float var = s2 * (1.f/HWC_) - mu*mu;
        const float rstd = rsqrtf(var + 1e-3f);
        mu_r[0] = mu * rstd; mu_r[1] = rstd;
      }
    }
    __syncthreads();
    if (tid < 32) a1s[tid] = ws[OFF_T + b*N_ + h*32 + tid] * mu_r[1];
    __syncthreads();
    const float murstd = mu_r[0];
    const size_t base = (size_t)(b*H_ + h)*(W_*C_);
    const float4* xp = (const float4*)(x + base);
    const float4* gp = (const float4*)(gamma + (size_t)h*(W_*C_));
    const float4* bp = (const float4*)(beta  + (size_t)h*(W_*C_));
    float4* op = (float4*)(out + base);
    #pragma unroll
    for (int k = 0; k < 8; ++k){
      const int f = tid + k*256;
      const float a1 = a1s[f >> 6];
      const float4 xv = xp[f], gv = gp[f], bv = bp[f];
      float4 o;
      o.x = fmaf(fmaf(xv.x, a1, -murstd), gv.x, bv.x);
      o.y = fmaf(fmaf(xv.y, a1, -murstd), gv.y, bv.y);
      o.z = fmaf(fmaf(xv.z, a1, -murstd), gv.z, bv.z);
      o.w = fmaf(fmaf(xv.w, a1, -murstd), gv.w, bv.w);
      op[f] = o;
    }
    __syncthreads();
  }
}

extern "C" void kernel_launch(void* const* d_in, const int* in_sizes, int n_in,
                              void* d_out, int out_size, void* d_ws, size_t ws_size,
                              hipStream_t stream){
  (void)in_sizes; (void)n_in; (void)out_size;
  if (ws_size < (size_t)WS_FLOATS * sizeof(float)) return;
  const float* x      = (const float*)d_in[0];
  const float* cc1_w  = (const float*)d_in[1];
  const float* cc1_b  = (const float*)d_in[2];
  const float* cc3_dw = (const float*)d_in[3];
  const float* cc3_pw = (const float*)d_in[4];
  const float* cc3_b  = (const float*)d_in[5];
  const float* ccd_w  = (const float*)d_in[6];
  const float* ccd_b  = (const float*)d_in[7];
  const float* ch1_w  = (const float*)d_in[8];
  const float* ch1_b  = (const float*)d_in[9];
  const float* ch3_dw = (const float*)d_in[10];
  const float* ch3_pw = (const float*)d_in[11];
  const float* ch3_b  = (const float*)d_in[12];
  const float* chd_w  = (const float*)d_in[13];
  const float* chd_b  = (const float*)d_in[14];
  const float* cw1_w  = (const float*)d_in[15];
  const float* cw1_b  = (const float*)d_in[16];
  const float* cw3_dw = (const float*)d_in[17];
  const float* cw3_pw = (const float*)d_in[18];
  const float* cw3_b  = (const float*)d_in[19];
  const float* cwd_w  = (const float*)d_in[20];
  const float* cwd_b  = (const float*)d_in[21];
  const float* branch_w = (const float*)d_in[22];
  const float* d1_w   = (const float*)d_in[23];
  const float* d1_b   = (const float*)d_in[24];
  const float* d2_w   = (const float*)d_in[25];
  const float* d2_b   = (const float*)d_in[26];
  const float* q_w    = (const float*)d_in[27];
  const float* q_b    = (const float*)d_in[28];
  const float* k_w    = (const float*)d_in[29];
  const float* k_b    = (const float*)d_in[30];
  const float* v_w    = (const float*)d_in[31];
  const float* v_b    = (const float*)d_in[32];
  const float* o_w    = (const float*)d_in[33];
  const float* o_b    = (const float*)d_in[34];
  const float* gamma  = (const float*)d_in[35];
  const float* beta   = (const float*)d_in[36];
  float* ws = (float*)d_ws;
  float* out = (float*)d_out;

  kAB<<<dim3(2048), dim3(256), 0, stream>>>(x, ws);
  kC<<<dim3(B_, 17), dim3(256), 0, stream>>>(ws,
      cc1_w, cc1_b, cc3_dw, cc3_pw, cc3_b, ccd_w, ccd_b,
      ch1_w, ch1_b, ch3_dw, ch3_pw, ch3_b, chd_w, chd_b,
      cw1_w, cw1_b, cw3_dw, cw3_pw, cw3_b, cwd_w, cwd_b,
      branch_w, d1_w, d1_b, d2_w, d2_b,
      q_w, q_b, k_w, k_b, v_w, v_b, o_w, o_b);
  kD<<<dim3(B_*64), dim3(256), 0, stream>>>(ws);
  kF<<<dim3(B_*H_), dim3(256), 0, stream>>>(x, gamma, beta, ws, out);
}

// Round 11
// 42.672 us; speedup vs baseline: 2.6287x; 2.6287x over previous
//
#include <hip/hip_runtime.h>

// TripletAttention on MI355X — 4-kernel pipeline.
// y = x * T[b,h,w] with T = 1 + S*cross*g; attention is rank-4
// (maps = mc * (ca, ha, wa)) so QK^T = u^T G u; AV+proj folded to
// dot = sum(ee * q_m)/Z with q_m precomputed per m.
// R10: kF pinned at 10.1us @63% HBM (near floor). kD v4: sub = (sh,sw)
// partition -> LDS reads tile all 32 banks (was 4-way conflict), NCOPY=1,
// 8KB LDS. kF: parallel LN finalize (R10 ship), de-probed.

#define B_   32
#define H_   32
#define W_   32
#define C_   256
#define N_   1024           // H_*W_
#define HWC_ (32*32*256)

// ws layout (float offsets)
#define OFF_XW    0          // [B][H][C]  mean over w
#define OFF_XH    262144     // [B][W][C]  mean over h
#define OFF_MC    524288     // [B][N]     mean over c
#define OFF_M2    557056     // [B][N]     sum of x^2 over c
#define OFF_T     589824     // [B][N]
#define OFF_HA    622592     // [B][32]
#define OFF_WA    623616     // [B][32]
#define OFF_CA    624640     // [B]
#define OFF_G     624672     // [B]
#define OFF_CST   624704     // 24 consts
#define OFF_LNP   624736     // [B][64][2] LN partials
#define WS_FLOATS 628832

#if __has_builtin(__builtin_amdgcn_exp2f)
#define EXP2F(x) __builtin_amdgcn_exp2f(x)
#else
#define EXP2F(x) exp2f(x)
#endif

__device__ __forceinline__ float sigm_(float v){ return 1.f/(1.f + __expf(-v)); }
__device__ __forceinline__ float dot4_(float4 a, float4 b){
  return a.x*b.x + a.y*b.y + a.z*b.z + a.w*b.w;
}

// ---------------- Kernel AB: blocks [0,1024): per-(b,h) slab -> xw, mc, m2
//                             blocks [1024,2048): per-(b,w) column -> xh
__global__ __launch_bounds__(256) void kAB(const float* __restrict__ x, float* __restrict__ ws){
  __shared__ float4 sl4[256];
  const int blk = blockIdx.x;
  const int tid = threadIdx.x, lane = tid & 63, wv = tid >> 6;
  if (blk < 1024){
    const int b = blk >> 5, h = blk & 31;
    const float* xp = x + (size_t)(b*H_ + h)*(W_*C_);
    float4 v[8];
    #pragma unroll
    for (int k = 0; k < 8; ++k) v[k] = ((const float4*)xp)[tid + k*256];
    #pragma unroll
    for (int k = 0; k < 8; ++k){
      float s = v[k].x + v[k].y + v[k].z + v[k].w;
      float q = v[k].x*v[k].x + v[k].y*v[k].y + v[k].z*v[k].z + v[k].w*v[k].w;
      #pragma unroll
      for (int d = 1; d < 64; d <<= 1){ s += __shfl_xor(s, d); q += __shfl_xor(q, d); }
      if (lane == 0){
        const int w = k*4 + wv;
        ws[OFF_MC + b*N_ + h*W_ + w] = s * (1.f/C_);
        ws[OFF_M2 + b*N_ + h*W_ + w] = q;
      }
    }
    float4 a = v[0];
    #pragma unroll
    for (int k = 1; k < 8; ++k){ a.x += v[k].x; a.y += v[k].y; a.z += v[k].z; a.w += v[k].w; }
    sl4[tid] = a;
    __syncthreads();
    if (tid < 64){
      const float4 p0 = sl4[tid], p1 = sl4[tid+64], p2 = sl4[tid+128], p3 = sl4[tid+192];
      float4 o;
      o.x = (p0.x+p1.x+p2.x+p3.x)*(1.f/W_);
      o.y = (p0.y+p1.y+p2.y+p3.y)*(1.f/W_);
      o.z = (p0.z+p1.z+p2.z+p3.z)*(1.f/W_);
      o.w = (p0.w+p1.w+p2.w+p3.w)*(1.f/W_);
      ((float4*)(ws + OFF_XW + (b*H_ + h)*C_))[tid] = o;
    }
  } else {
    const int blk2 = blk - 1024, b = blk2 >> 5, w = blk2 & 31;
    const int hh = tid >> 6, c4 = (tid & 63)*4;
    const float* xp = x + (size_t)b*HWC_ + (size_t)w*C_ + c4;
    float4 acc = {0.f,0.f,0.f,0.f};
    #pragma unroll
    for (int hb = 0; hb < 8; ++hb){
      const int h = hb*4 + hh;
      const float4 v = *(const float4*)(xp + (size_t)h*(W_*C_));
      acc.x += v.x; acc.y += v.y; acc.z += v.z; acc.w += v.w;
    }
    sl4[tid] = acc;
    __syncthreads();
    if (tid < 64){
      const float4 a = sl4[tid], b2 = sl4[tid+64], c = sl4[tid+128], d = sl4[tid+192];
      float4 o;
      o.x = (a.x+b2.x+c.x+d.x)*(1.f/H_);
      o.y = (a.y+b2.y+c.y+d.y)*(1.f/H_);
      o.z = (a.z+b2.z+c.z+d.z)*(1.f/H_);
      o.w = (a.w+b2.w+c.w+d.w)*(1.f/H_);
      *(float4*)&ws[OFF_XH + (b*W_ + w)*C_ + tid*4] = o;
    }
  }
}

// ---------------- Kernel C: one wave per (profile,row) gate output
// grid (B_, 17): y in [0,8) -> ha rows, y in [8,16) -> wa rows, y==16 -> ca/g/consts
__global__ __launch_bounds__(256) void kC(float* __restrict__ ws,
  const float* __restrict__ cc1_w, const float* __restrict__ cc1_b, const float* __restrict__ cc3_dw,
  const float* __restrict__ cc3_pw, const float* __restrict__ cc3_b, const float* __restrict__ ccd_w, const float* __restrict__ ccd_b,
  const float* __restrict__ ch1_w, const float* __restrict__ ch1_b, const float* __restrict__ ch3_dw,
  const float* __restrict__ ch3_pw, const float* __restrict__ ch3_b, const float* __restrict__ chd_w, const float* __restrict__ chd_b,
  const float* __restrict__ cw1_w, const float* __restrict__ cw1_b, const float* __restrict__ cw3_dw,
  const float* __restrict__ cw3_pw, const float* __restrict__ cw3_b, const float* __restrict__ cwd_w, const float* __restrict__ cwd_b,
  const float* __restrict__ branch_w, const float* __restrict__ d1_w, const float* __restrict__ d1_b,
  const float* __restrict__ d2_w, const float* __restrict__ d2_b,
  const float* __restrict__ q_w, const float* __restrict__ q_b, const float* __restrict__ k_w, const float* __restrict__ k_b,
  const float* __restrict__ v_w, const float* __restrict__ v_b, const float* __restrict__ o_w, const float* __restrict__ o_b)
{
  const int b = blockIdx.x, y = blockIdx.y;
  const int tid = threadIdx.x, lane = tid & 63, wv = tid >> 6;

  if (y < 16){
    const int prof = y >> 3;                 // 0: height gates from xw, 1: width gates from xh
    const int h = ((y & 7) << 2) | wv;       // 0..31, one per wave
    const float* P  = ws + (prof ? OFF_XH : OFF_XW) + b*(32*C_);
    const float* w1 = prof ? cw1_w  : ch1_w;
    const float* b1 = prof ? cw1_b  : ch1_b;
    const float* dw = prof ? cw3_dw : ch3_dw;
    const float* pw = prof ? cw3_pw : ch3_pw;
    const float* b3 = prof ? cw3_b  : ch3_b;
    const float* wd = prof ? cwd_w  : chd_w;
    const float* bd = prof ? cwd_b  : chd_b;
    const int c4 = lane*4;
    const float4 z4 = {0.f,0.f,0.f,0.f};
    const float4 r0  = *(const float4*)(P + h*C_ + c4);
    const float4 rm1 = (h > 0)  ? *(const float4*)(P + (h-1)*C_ + c4) : z4;
    const float4 rp1 = (h < 31) ? *(const float4*)(P + (h+1)*C_ + c4) : z4;
    const float4 rm2 = (h > 1)  ? *(const float4*)(P + (h-2)*C_ + c4) : z4;
    const float4 rp2 = (h < 30) ? *(const float4*)(P + (h+2)*C_ + c4) : z4;
    const float4 w1q = *(const float4*)(w1 + c4);
    const float4 d3  = *(const float4*)(dw + 3*C_ + c4);
    const float4 d4  = *(const float4*)(dw + 4*C_ + c4);
    const float4 d5  = *(const float4*)(dw + 5*C_ + c4);
    const float4 pwq = *(const float4*)(pw + c4);
    const float4 g3  = *(const float4*)(wd + 3*C_ + c4);
    const float4 g4  = *(const float4*)(wd + 4*C_ + c4);
    const float4 g5  = *(const float4*)(wd + 5*C_ + c4);
    float s1 = dot4_(r0, w1q);
    float4 dv;
    dv.x = rm1.x*d3.x + r0.x*d4.x + rp1.x*d5.x;
    dv.y = rm1.y*d3.y + r0.y*d4.y + rp1.y*d5.y;
    dv.z = rm1.z*d3.z + r0.z*d4.z + rp1.z*d5.z;
    dv.w = rm1.w*d3.w + r0.w*d4.w + rp1.w*d5.w;
    float s3 = dot4_(dv, pwq);
    float sd = (rm2.x*g3.x + r0.x*g4.x + rp2.x*g5.x)
             + (rm2.y*g3.y + r0.y*g4.y + rp2.y*g5.y)
             + (rm2.z*g3.z + r0.z*g4.z + rp2.z*g5.z)
             + (rm2.w*g3.w + r0.w*g4.w + rp2.w*g5.w);
    #pragma unroll
    for (int d = 1; d < 64; d <<= 1){ s1 += __shfl_xor(s1,d); s3 += __shfl_xor(s3,d); sd += __shfl_xor(sd,d); }
    if (lane == 0)
      ws[(prof ? OFF_WA : OFF_HA) + b*32 + h] =
          (sigm_(s1 + b1[0]) + sigm_(s3 + b3[0]) + sigm_(sd + bd[0])) * (1.f/3.f);
    return;
  }

  // y == 16: gvec -> ca (wave0), g (wave1, parallel SE); consts (wave2, b==0)
  __shared__ float gvec[C_];
  { float s = 0.f;
    const float* P = ws + OFF_XW + b*(32*C_);
    #pragma unroll
    for (int h = 0; h < H_; ++h) s += P[h*C_ + tid];
    gvec[tid] = s * (1.f/H_); }
  __syncthreads();

  if (wv == 0){
    float s1 = 0.f, s3 = 0.f, sd = 0.f;
    #pragma unroll
    for (int k = 0; k < 4; ++k){
      const int c = lane + k*64;
      const float v = gvec[c];
      s1 = fmaf(v, cc1_w[c], s1);
      s3 = fmaf(v*cc3_dw[4*C_+c], cc3_pw[c], s3);
      sd = fmaf(v, ccd_w[4*C_+c], sd);
    }
    #pragma unroll
    for (int d = 1; d < 64; d <<= 1){ s1 += __shfl_xor(s1,d); s3 += __shfl_xor(s3,d); sd += __shfl_xor(sd,d); }
    if (lane == 0)
      ws[OFF_CA + b] = (sigm_(s1+cc1_b[0]) + sigm_(s3+cc3_b[0]) + sigm_(sd+ccd_b[0])) * (1.f/3.f);
  } else if (wv == 1){
    // parallel SE: lane = (cg, r): 4 channel-groups x 16 hidden units
    const int r16 = lane & 15, cg = lane >> 4;
    float s = 0.f;
    #pragma unroll
    for (int i = 0; i < 64; ++i){
      const int c = cg*64 + i;
      s = fmaf(gvec[c], d1_w[c*16 + r16], s);
    }
    s += __shfl_xor(s, 16); s += __shfl_xor(s, 32);
    float t = fmaxf(s + d1_b[r16], 0.f) * d2_w[r16];
    t += __shfl_xor(t, 1); t += __shfl_xor(t, 2); t += __shfl_xor(t, 4); t += __shfl_xor(t, 8);
    if (lane == 0) ws[OFF_G + b] = sigm_(t + d2_b[0]);
  } else if (wv == 2 && b == 0){
    if (lane < 16){
      const int i = lane >> 2, j = lane & 3;
      float s = 0.f;
      #pragma unroll
      for (int d = 0; d < 8; ++d){
        const float qv = (i < 3) ? q_w[i*8+d] : q_b[d];
        const float kv = (j < 3) ? k_w[j*8+d] : k_b[d];
        s = fmaf(qv, kv, s);
      }
      ws[OFF_CST + i*4 + j] = s * 0.51010305898f;   // log2(e)/sqrt(8)
    } else if (lane < 19){
      const int i = lane - 16;
      float s = 0.f;
      #pragma unroll
      for (int d = 0; d < 8; ++d) s = fmaf(v_w[i*8+d], o_w[d], s);
      ws[OFF_CST + lane] = s;
    } else if (lane == 19){
      float s = o_b[0];
      #pragma unroll
      for (int d = 0; d < 8; ++d) s = fmaf(v_b[d], o_w[d], s);
      ws[OFF_CST + 19] = s;
    } else if (lane == 20){
      const float b0 = branch_w[0], b1 = branch_w[1], b2 = branch_w[2];
      const float mx = fmaxf(b0, fmaxf(b1, b2));
      const float e0 = __expf(b0-mx), e1 = __expf(b1-mx), e2 = __expf(b2-mx);
      const float inv = 1.f/(e0+e1+e2);
      ws[OFF_CST+20] = e0*inv; ws[OFF_CST+21] = e1*inv; ws[OFF_CST+22] = e2*inv;
      ws[OFF_CST+23] = 0.f;
    }
  }
}

// ---------------- Kernel D v4: conflict-free sub = (sh,sw) partition, NCOPY=1
// 2048 blocks (b, rblk<64): 16 rows; sub sh in {0,1} x sw in {0..7}:
// hm = sh*16+i (i<16), wm = 4*sw..+3. LDS read banks = 4*sw -> tiles all 32.
__global__ __launch_bounds__(256, 4) void kD(float* __restrict__ ws){
  __shared__ __align__(16) float mcs[N_];   // 4 KB
  __shared__ __align__(16) float qs [N_];   // 4 KB
  __shared__ float ha_s[32], wa_s[32], cst[24], sc[2], red[8];
  const int blk = blockIdx.x, b = blk >> 6, rblk = blk & 63;
  const int tid = threadIdx.x, lane = tid & 63, wv = tid >> 6;
  const int r = tid >> 4, sub = tid & 15;
  const int sh = sub >> 3, sw = sub & 7;
  const int n = rblk*16 + r;
  const int hn = n >> 5, wn = n & 31;

  // global loads issued early
  const float4 v  = ((const float4*)(ws + OFF_MC + b*N_))[tid];
  const float m2v = ws[OFF_M2 + b*N_ + n];
  const float mcn = ws[OFF_MC + b*N_ + n];
  if (tid < 32){ ha_s[tid] = ws[OFF_HA + b*32 + tid]; wa_s[tid] = ws[OFF_WA + b*32 + tid]; }
  else if (tid >= 64 && tid < 88) cst[tid-64] = ws[OFF_CST + (tid-64)];
  else if (tid == 96){ sc[0] = ws[OFF_CA + b]; sc[1] = ws[OFF_G + b]; }
  *(float4*)&mcs[tid*4] = v;
  __syncthreads();

  // q_m = mc_m * (ca*z0 + z1*ha_hm + z2*wa_wm) for this thread's 4 m's
  const float ca = sc[0], gg = sc[1];
  {
    const int hm0 = tid >> 3;
    const int wm0 = (tid*4) & 31;
    const float base = ca*cst[16] + cst[17]*ha_s[hm0];
    float4 q;
    q.x = v.x * (base + cst[18]*wa_s[wm0+0]);
    q.y = v.y * (base + cst[18]*wa_s[wm0+1]);
    q.z = v.z * (base + cst[18]*wa_s[wm0+2]);
    q.w = v.w * (base + cst[18]*wa_s[wm0+3]);
    *(float4*)&qs[tid*4] = q;
  }
  __syncthreads();

  const float u0 = mcn*ca, u1 = mcn*ha_s[hn], u2 = mcn*wa_s[wn];
  const float p0 = u0*cst[0] + u1*cst[4] + u2*cst[8]  + cst[12];
  const float p1 = u0*cst[1] + u1*cst[5] + u2*cst[9]  + cst[13];
  const float p2 = u0*cst[2] + u1*cst[6] + u2*cst[10] + cst[14];
  const float p3 = u0*cst[3] + u1*cst[7] + u2*cst[11] + cst[15];
  const float pc = p0 * ca;

  // wa slice and p2*wa hoisted to registers (constant per thread)
  const float4 w4 = *(const float4*)&wa_s[4*sw];
  float4 pw;
  pw.x = p2*w4.x; pw.y = p2*w4.y; pw.z = p2*w4.z; pw.w = p2*w4.w;

  float Z = 0.f, ACC = 0.f;
  #pragma unroll
  for (int i = 0; i < 16; ++i){
    const int hm = sh*16 + i;
    const float th = fmaf(p1, ha_s[hm], pc);
    const float4 m4 = *(const float4*)&mcs[hm*32 + 4*sw];
    const float4 q4 = *(const float4*)&qs [hm*32 + 4*sw];
    { const float ee = EXP2F(fmaf(m4.x, th + pw.x, p3)); Z += ee; ACC = fmaf(ee, q4.x, ACC); }
    { const float ee = EXP2F(fmaf(m4.y, th + pw.y, p3)); Z += ee; ACC = fmaf(ee, q4.y, ACC); }
    { const float ee = EXP2F(fmaf(m4.z, th + pw.z, p3)); Z += ee; ACC = fmaf(ee, q4.z, ACC); }
    { const float ee = EXP2F(fmaf(m4.w, th + pw.w, p3)); Z += ee; ACC = fmaf(ee, q4.w, ACC); }
  }
  #pragma unroll
  for (int d = 1; d < 16; d <<= 1){
    Z   += __shfl_xor(Z, d);
    ACC += __shfl_xor(ACC, d);
  }

  float t1 = 0.f, t2 = 0.f;
  if (sub == 0){
    const float dot = ACC / Z + cst[19];
    const float cross = 1.f / (1.f + __expf(-dot));
    const float S = cst[20]*ca + cst[21]*ha_s[hn] + cst[22]*wa_s[wn];
    const float T = fmaf(S*cross, gg, 1.f);
    ws[OFF_T + b*N_ + n] = T;
    t1 = T * mcn * (float)C_;
    t2 = T * T * m2v;
  }
  #pragma unroll
  for (int d = 1; d < 64; d <<= 1){ t1 += __shfl_xor(t1,d); t2 += __shfl_xor(t2,d); }
  if (lane == 0){ red[wv] = t1; red[4+wv] = t2; }
  __syncthreads();
  if (tid == 0){
    ws[OFF_LNP + (b*64 + rblk)*2 + 0] = red[0]+red[1]+red[2]+red[3];
    ws[OFF_LNP + (b*64 + rblk)*2 + 1] = red[4]+red[5]+red[6]+red[7];
  }
}

// ---------------- Kernel F: parallel LN finalize + stream
__global__ __launch_bounds__(256) void kF(const float* __restrict__ x, const float* __restrict__ gamma,
                                          const float* __restrict__ beta, const float* __restrict__ ws,
                                          float* __restrict__ out){
  const int blk = blockIdx.x, b = blk >> 5, h = blk & 31;
  const int tid = threadIdx.x;
  __shared__ float a1s[32];
  __shared__ float mu_r[2];
  if (tid < 64){
    float s1 = ws[OFF_LNP + (b*64 + tid)*2 + 0];
    float s2 = ws[OFF_LNP + (b*64 + tid)*2 + 1];
    #pragma unroll
    for (int d = 1; d < 64; d <<= 1){ s1 += __shfl_xor(s1, d); s2 += __shfl_xor(s2, d); }
    if (tid == 0){
      const float mu  = s1 * (1.f/HWC_);
      const float var = s2 * (1.f/HWC_) - mu*mu;
      const float rstd = rsqrtf(var + 1e-3f);
      mu_r[0] = mu * rstd; mu_r[1] = rstd;
    }
  }
  __syncthreads();
  if (tid < 32) a1s[tid] = ws[OFF_T + b*N_ + h*32 + tid] * mu_r[1];
  __syncthreads();
  const float murstd = mu_r[0];
  const size_t base = (size_t)(b*H_ + h)*(W_*C_);
  const float4* xp = (const float4*)(x + base);
  const float4* gp = (const float4*)(gamma + (size_t)h*(W_*C_));
  const float4* bp = (const float4*)(beta  + (size_t)h*(W_*C_));
  float4* op = (float4*)(out + base);
  #pragma unroll
  for (int k = 0; k < 8; ++k){
    const int f = tid + k*256;
    const float a1 = a1s[f >> 6];
    const float4 xv = xp[f], gv = gp[f], bv = bp[f];
    float4 o;
    o.x = fmaf(fmaf(xv.x, a1, -murstd), gv.x, bv.x);
    o.y = fmaf(fmaf(xv.y, a1, -murstd), gv.y, bv.y);
    o.z = fmaf(fmaf(xv.z, a1, -murstd), gv.z, bv.z);
    o.w = fmaf(fmaf(xv.w, a1, -murstd), gv.w, bv.w);
    op[f] = o;
  }
}

extern "C" void kernel_launch(void* const* d_in, const int* in_sizes, int n_in,
                              void* d_out, int out_size, void* d_ws, size_t ws_size,
                              hipStream_t stream){
  (void)in_sizes; (void)n_in; (void)out_size;
  if (ws_size < (size_t)WS_FLOATS * sizeof(float)) return;
  const float* x      = (const float*)d_in[0];
  const float* cc1_w  = (const float*)d_in[1];
  const float* cc1_b  = (const float*)d_in[2];
  const float* cc3_dw = (const float*)d_in[3];
  const float* cc3_pw = (const float*)d_in[4];
  const float* cc3_b  = (const float*)d_in[5];
  const float* ccd_w  = (const float*)d_in[6];
  const float* ccd_b  = (const float*)d_in[7];
  const float* ch1_w  = (const float*)d_in[8];
  const float* ch1_b  = (const float*)d_in[9];
  const float* ch3_dw = (const float*)d_in[10];
  const float* ch3_pw = (const float*)d_in[11];
  const float* ch3_b  = (const float*)d_in[12];
  const float* chd_w  = (const float*)d_in[13];
  const float* chd_b  = (const float*)d_in[14];
  const float* cw1_w  = (const float*)d_in[15];
  const float* cw1_b  = (const float*)d_in[16];
  const float* cw3_dw = (const float*)d_in[17];
  const float* cw3_pw = (const float*)d_in[18];
  const float* cw3_b  = (const float*)d_in[19];
  const float* cwd_w  = (const float*)d_in[20];
  const float* cwd_b  = (const float*)d_in[21];
  const float* branch_w = (const float*)d_in[22];
  const float* d1_w   = (const float*)d_in[23];
  const float* d1_b   = (const float*)d_in[24];
  const float* d2_w   = (const float*)d_in[25];
  const float* d2_b   = (const float*)d_in[26];
  const float* q_w    = (const float*)d_in[27];
  const float* q_b    = (const float*)d_in[28];
  const float* k_w    = (const float*)d_in[29];
  const float* k_b    = (const float*)d_in[30];
  const float* v_w    = (const float*)d_in[31];
  const float* v_b    = (const float*)d_in[32];
  const float* o_w    = (const float*)d_in[33];
  const float* o_b    = (const float*)d_in[34];
  const float* gamma  = (const float*)d_in[35];
  const float* beta   = (const float*)d_in[36];
  float* ws = (float*)d_ws;
  float* out = (float*)d_out;

  kAB<<<dim3(2048), dim3(256), 0, stream>>>(x, ws);
  kC<<<dim3(B_, 17), dim3(256), 0, stream>>>(ws,
      cc1_w, cc1_b, cc3_dw, cc3_pw, cc3_b, ccd_w, ccd_b,
      ch1_w, ch1_b, ch3_dw, ch3_pw, ch3_b, chd_w, chd_b,
      cw1_w, cw1_b, cw3_dw, cw3_pw, cw3_b, cwd_w, cwd_b,
      branch_w, d1_w, d1_b, d2_w, d2_b,
      q_w, q_b, k_w, k_b, v_w, v_b, o_w, o_b);
  kD<<<dim3(B_*64), dim3(256), 0, stream>>>(ws);
  kF<<<dim3(B_*H_), dim3(256), 0, stream>>>(x, gamma, beta, ws, out);
}